// Round 3
// baseline (258.672 us; speedup 1.0000x reference)
//
#include <hip/hip_runtime.h>

// BayesianLinear: out0 = x @ (mu + exp(ls)*eps)^T + (bmu + exp(bls)*eb)
//                 out1 = sqrt( x^2 @ (exp(ls)^2)^T + exp(bls)^2 )
// B=4096, IN=2048, OUT=2048, all fp32 in/out.
// R3: TM 128->64 => grid 512->1024 blocks (2->4 blocks/CU). R2 showed
// occupancy 21% / MfmaUtil 28% / VALUBusy 15% -- latency-bound on the
// vmcnt(0) barrier drain with only 2 resident blocks/CU. Keep R2's
// zero-conflict XOR swizzle + XCD remap.

#define B_DIM   4096
#define IN_DIM  2048
#define OUT_DIM 2048

#define TM 64
#define TN 128
#define BK 32

typedef __attribute__((ext_vector_type(8))) short  short8;
typedef __attribute__((ext_vector_type(4))) float  floatx4;

__device__ __forceinline__ short f2bf(float f) {
    unsigned int u = __float_as_uint(f);
    u += 0x7fffu + ((u >> 16) & 1u);
    return (short)(u >> 16);
}

__device__ __forceinline__ void cp16(const void* g, void* l) {
    __builtin_amdgcn_global_load_lds(
        (const __attribute__((address_space(1))) unsigned int*)g,
        (__attribute__((address_space(3))) unsigned int*)l,
        16, 0, 0);
}

// ---- fused prep: blocks [0,2048) do W/S2, blocks [2048,6144) do X/X2 ----
__global__ void prep_kernel(const float* __restrict__ mu,
                            const float* __restrict__ ls,
                            const float* __restrict__ ew,
                            const float* __restrict__ x,
                            short* __restrict__ wbf,
                            short* __restrict__ s2bf,
                            short* __restrict__ xbf,
                            short* __restrict__ x2bf) {
    int bid = blockIdx.x;
    if (bid < 2048) {
        int i = bid * 256 + threadIdx.x;          // over OUT*IN/8
        const float4* mu4 = (const float4*)mu;
        const float4* ls4 = (const float4*)ls;
        const float4* ew4 = (const float4*)ew;
        float4 m0 = mu4[2 * i], m1 = mu4[2 * i + 1];
        float4 L0 = ls4[2 * i], L1 = ls4[2 * i + 1];
        float4 e0 = ew4[2 * i], e1 = ew4[2 * i + 1];
        float s[8] = {__expf(L0.x), __expf(L0.y), __expf(L0.z), __expf(L0.w),
                      __expf(L1.x), __expf(L1.y), __expf(L1.z), __expf(L1.w)};
        float mm[8] = {m0.x, m0.y, m0.z, m0.w, m1.x, m1.y, m1.z, m1.w};
        float ee[8] = {e0.x, e0.y, e0.z, e0.w, e1.x, e1.y, e1.z, e1.w};
        short8 wo, so;
        #pragma unroll
        for (int j = 0; j < 8; ++j) {
            wo[j] = f2bf(fmaf(s[j], ee[j], mm[j]));
            so[j] = f2bf(s[j] * s[j]);
        }
        ((short8*)wbf)[i]  = wo;
        ((short8*)s2bf)[i] = so;
    } else {
        int i = (bid - 2048) * 256 + threadIdx.x; // over B*IN/8
        const float4* x4 = (const float4*)x;
        float4 v0 = x4[2 * i], v1 = x4[2 * i + 1];
        float vv[8] = {v0.x, v0.y, v0.z, v0.w, v1.x, v1.y, v1.z, v1.w};
        short8 xo, x2o;
        #pragma unroll
        for (int j = 0; j < 8; ++j) {
            xo[j]  = f2bf(vv[j]);
            x2o[j] = f2bf(vv[j] * vv[j]);
        }
        ((short8*)xbf)[i]  = xo;
        ((short8*)x2bf)[i] = x2o;
    }
}

// ---- fused dual GEMM (NT): C1 = Xbf @ Wbf^T, C2 = X2bf @ S2bf^T ----
// 256 thr = 4 waves (2x2); block tile 64x128; wave tile 32x64 (2x4 MFMA 16x16x32)
// LDS chunk-column XOR swizzle: LDS col c of row r holds global chunk c^((r>>1)&3)
__global__ __launch_bounds__(256, 4) void dual_gemm_kernel(
    const short* __restrict__ xb,  const short* __restrict__ x2b,
    const short* __restrict__ wb,  const short* __restrict__ s2b,
    const float* __restrict__ bmu, const float* __restrict__ bls,
    const float* __restrict__ beps, float* __restrict__ out)
{
    __shared__ __align__(16) short xs[TM * BK];    // 64x32
    __shared__ __align__(16) short x2s[TM * BK];
    __shared__ __align__(16) short ws[TN * BK];    // 128x32
    __shared__ __align__(16) short s2s[TN * BK];

    const int tid = threadIdx.x;
    const int l   = tid & 63;
    const int wv  = tid >> 6;
    const int wr  = wv >> 1;       // wave m (0..1), 32 rows each
    const int wc  = wv & 1;        // wave n (0..1), 64 cols each

    // XCD-aware remap over 1024 blocks: lid%8 = XCD, each XCD a 16x8 tile region
    const int lid = blockIdx.y * gridDim.x + blockIdx.x;   // 0..1023
    const int xcd = lid & 7;
    const int j   = lid >> 3;                              // 0..127
    const int m0  = ((xcd & 3) * 16 + (j >> 3)) * TM;      // 64 m-tiles
    const int n0  = ((xcd >> 2) * 8 + (j & 7)) * TN;       // 16 n-tiles

    floatx4 acc1[2][4] = {};
    floatx4 acc2[2][4] = {};

    // MFMA A/B frag geometry: row = lane&15, k-quad q = lane>>4
    const int rA  = l & 15;
    const int q   = l >> 4;
    const int swz16 = (q ^ ((rA >> 1) & 3)) * 16;   // per-lane, loop-invariant

    // staging: chunk ci = qq*256 + tid; row = ci>>2; swizzled global chunk col
    const int row0s = tid >> 2;          // 0..63
    const int row1s = 64 + (tid >> 2);   // 64..127 (B tiles only)
    const int kcs   = ((tid & 3) ^ ((tid >> 3) & 3)) * 16;
    const int lb0 = (wv * 64) * 16;
    const int lb1 = (256 + wv * 64) * 16;

    const char* xbp  = (const char*)xb;
    const char* x2bp = (const char*)x2b;
    const char* wbp  = (const char*)wb;
    const char* s2bp = (const char*)s2b;

    for (int k0 = 0; k0 < IN_DIM; k0 += BK) {
        size_t gx0 = ((size_t)(m0 + row0s) * IN_DIM + k0) * 2 + kcs;
        size_t gw0 = ((size_t)(n0 + row0s) * IN_DIM + k0) * 2 + kcs;
        size_t gw1 = ((size_t)(n0 + row1s) * IN_DIM + k0) * 2 + kcs;
        cp16(xbp  + gx0, (char*)xs  + lb0);
        cp16(x2bp + gx0, (char*)x2s + lb0);
        cp16(wbp  + gw0, (char*)ws  + lb0);
        cp16(wbp  + gw1, (char*)ws  + lb1);
        cp16(s2bp + gw0, (char*)s2s + lb0);
        cp16(s2bp + gw1, (char*)s2s + lb1);
        __syncthreads();

        {
            short8 a[2], b[4];
            #pragma unroll
            for (int mt = 0; mt < 2; ++mt)
                a[mt] = *(const short8*)((const char*)xs + (wr * 32 + mt * 16 + rA) * 64 + swz16);
            #pragma unroll
            for (int nt = 0; nt < 4; ++nt)
                b[nt] = *(const short8*)((const char*)ws + (wc * 64 + nt * 16 + rA) * 64 + swz16);
            #pragma unroll
            for (int mt = 0; mt < 2; ++mt)
                #pragma unroll
                for (int nt = 0; nt < 4; ++nt)
                    acc1[mt][nt] = __builtin_amdgcn_mfma_f32_16x16x32_bf16(
                        a[mt], b[nt], acc1[mt][nt], 0, 0, 0);
        }
        {
            short8 a[2], b[4];
            #pragma unroll
            for (int mt = 0; mt < 2; ++mt)
                a[mt] = *(const short8*)((const char*)x2s + (wr * 32 + mt * 16 + rA) * 64 + swz16);
            #pragma unroll
            for (int nt = 0; nt < 4; ++nt)
                b[nt] = *(const short8*)((const char*)s2s + (wc * 64 + nt * 16 + rA) * 64 + swz16);
            #pragma unroll
            for (int mt = 0; mt < 2; ++mt)
                #pragma unroll
                for (int nt = 0; nt < 4; ++nt)
                    acc2[mt][nt] = __builtin_amdgcn_mfma_f32_16x16x32_bf16(
                        a[mt], b[nt], acc2[mt][nt], 0, 0, 0);
        }
        __syncthreads();
    }

    // epilogue: C/D layout col = lane&15, row = (lane>>4)*4 + reg
    const int rq = (l >> 4) * 4;
    const size_t outOff = (size_t)B_DIM * OUT_DIM;
    #pragma unroll
    for (int nt = 0; nt < 4; ++nt) {
        int col = n0 + wc * 64 + nt * 16 + (l & 15);
        float bsig = __expf(bls[col]);
        float bv   = fmaf(bsig, beps[col], bmu[col]);
        float bs2v = bsig * bsig;
        #pragma unroll
        for (int mt = 0; mt < 2; ++mt) {
            int row = m0 + wr * 32 + mt * 16 + rq;
            #pragma unroll
            for (int r = 0; r < 4; ++r) {
                size_t idx = (size_t)(row + r) * OUT_DIM + col;
                out[idx]          = acc1[mt][nt][r] + bv;
                out[outOff + idx] = sqrtf(acc2[mt][nt][r] + bs2v);
            }
        }
    }
}

// ---- slow fp32 fallback (only if d_ws is too small) ----
__global__ void fallback_kernel(const float* __restrict__ x,
                                const float* __restrict__ wmu,
                                const float* __restrict__ wls,
                                const float* __restrict__ bmu,
                                const float* __restrict__ bls,
                                const float* __restrict__ ew,
                                const float* __restrict__ eb,
                                float* __restrict__ out) {
    int idx = blockIdx.x * blockDim.x + threadIdx.x;
    int b = idx / OUT_DIM, o = idx % OUT_DIM;
    float acc = 0.f, accv = 0.f;
    const float* xr = x   + (size_t)b * IN_DIM;
    const float* mr = wmu + (size_t)o * IN_DIM;
    const float* lr = wls + (size_t)o * IN_DIM;
    const float* er = ew  + (size_t)o * IN_DIM;
    for (int k = 0; k < IN_DIM; ++k) {
        float sg = __expf(lr[k]);
        float wv = fmaf(sg, er[k], mr[k]);
        float xv = xr[k];
        acc  = fmaf(xv, wv, acc);
        accv = fmaf(xv * xv, sg * sg, accv);
    }
    float bsig = __expf(bls[o]);
    out[idx] = acc + fmaf(bsig, eb[o], bmu[o]);
    out[(size_t)B_DIM * OUT_DIM + idx] = sqrtf(accv + bsig * bsig);
}

extern "C" void kernel_launch(void* const* d_in, const int* in_sizes, int n_in,
                              void* d_out, int out_size, void* d_ws, size_t ws_size,
                              hipStream_t stream) {
    const float* x   = (const float*)d_in[0];
    const float* wmu = (const float*)d_in[1];
    const float* wls = (const float*)d_in[2];
    const float* bmu = (const float*)d_in[3];
    const float* bls = (const float*)d_in[4];
    const float* ew  = (const float*)d_in[5];
    const float* eb  = (const float*)d_in[6];
    float* out = (float*)d_out;

    const size_t wn = (size_t)OUT_DIM * IN_DIM;
    const size_t xn = (size_t)B_DIM * IN_DIM;
    const size_t need = (2 * wn + 2 * xn) * sizeof(short);

    if (ws_size < need) {
        int total = B_DIM * OUT_DIM;
        fallback_kernel<<<(total + 255) / 256, 256, 0, stream>>>(
            x, wmu, wls, bmu, bls, ew, eb, out);
        return;
    }

    short* wbf  = (short*)d_ws;
    short* s2bf = wbf + wn;
    short* xbf  = s2bf + wn;
    short* x2bf = xbf + xn;

    prep_kernel<<<6144, 256, 0, stream>>>(wmu, wls, ew, x, wbf, s2bf, xbf, x2bf);

    dim3 grid(OUT_DIM / TN, B_DIM / TM);   // (16, 64) = 1024 blocks
    dual_gemm_kernel<<<grid, 256, 0, stream>>>(
        xbf, x2bf, wbf, s2bf, bmu, bls, eb, out);
}

// Round 4
// 223.350 us; speedup vs baseline: 1.1581x; 1.1581x over previous
//
#include <hip/hip_runtime.h>

// BayesianLinear: out0 = x @ (mu + exp(ls)*eps)^T + (bmu + exp(bls)*eb)
//                 out1 = sqrt( x^2 @ (exp(ls)^2)^T + exp(bls)^2 )
// B=4096, IN=2048, OUT=2048, all fp32 in/out.
// R4: revert to 128x128 tile (R3 showed tile shrink hurts: intensity rules,
// not occupancy) + switch 16x16x32 -> 32x32x16 MFMA (m119: +20% pipe
// efficiency, half the MFMA instrs, full-cacheline epilogue stores).

#define B_DIM   4096
#define IN_DIM  2048
#define OUT_DIM 2048

#define TM 128
#define TN 128
#define BK 32

typedef __attribute__((ext_vector_type(8)))  short  short8;
typedef __attribute__((ext_vector_type(16))) float  floatx16;

__device__ __forceinline__ short f2bf(float f) {
    unsigned int u = __float_as_uint(f);
    u += 0x7fffu + ((u >> 16) & 1u);
    return (short)(u >> 16);
}

__device__ __forceinline__ void cp16(const void* g, void* l) {
    __builtin_amdgcn_global_load_lds(
        (const __attribute__((address_space(1))) unsigned int*)g,
        (__attribute__((address_space(3))) unsigned int*)l,
        16, 0, 0);
}

// ---- fused prep: blocks [0,2048) do W/S2, blocks [2048,6144) do X/X2 ----
__global__ void prep_kernel(const float* __restrict__ mu,
                            const float* __restrict__ ls,
                            const float* __restrict__ ew,
                            const float* __restrict__ x,
                            short* __restrict__ wbf,
                            short* __restrict__ s2bf,
                            short* __restrict__ xbf,
                            short* __restrict__ x2bf) {
    int bid = blockIdx.x;
    if (bid < 2048) {
        int i = bid * 256 + threadIdx.x;          // over OUT*IN/8
        const float4* mu4 = (const float4*)mu;
        const float4* ls4 = (const float4*)ls;
        const float4* ew4 = (const float4*)ew;
        float4 m0 = mu4[2 * i], m1 = mu4[2 * i + 1];
        float4 L0 = ls4[2 * i], L1 = ls4[2 * i + 1];
        float4 e0 = ew4[2 * i], e1 = ew4[2 * i + 1];
        float s[8] = {__expf(L0.x), __expf(L0.y), __expf(L0.z), __expf(L0.w),
                      __expf(L1.x), __expf(L1.y), __expf(L1.z), __expf(L1.w)};
        float mm[8] = {m0.x, m0.y, m0.z, m0.w, m1.x, m1.y, m1.z, m1.w};
        float ee[8] = {e0.x, e0.y, e0.z, e0.w, e1.x, e1.y, e1.z, e1.w};
        short8 wo, so;
        #pragma unroll
        for (int j = 0; j < 8; ++j) {
            wo[j] = f2bf(fmaf(s[j], ee[j], mm[j]));
            so[j] = f2bf(s[j] * s[j]);
        }
        ((short8*)wbf)[i]  = wo;
        ((short8*)s2bf)[i] = so;
    } else {
        int i = (bid - 2048) * 256 + threadIdx.x; // over B*IN/8
        const float4* x4 = (const float4*)x;
        float4 v0 = x4[2 * i], v1 = x4[2 * i + 1];
        float vv[8] = {v0.x, v0.y, v0.z, v0.w, v1.x, v1.y, v1.z, v1.w};
        short8 xo, x2o;
        #pragma unroll
        for (int j = 0; j < 8; ++j) {
            xo[j]  = f2bf(vv[j]);
            x2o[j] = f2bf(vv[j] * vv[j]);
        }
        ((short8*)xbf)[i]  = xo;
        ((short8*)x2bf)[i] = x2o;
    }
}

// ---- fused dual GEMM (NT): C1 = Xbf @ Wbf^T, C2 = X2bf @ S2bf^T ----
// 256 thr = 4 waves (2x2); block tile 128x128; wave tile 64x64 per GEMM
// = 2x2 MFMA 32x32x16, BK=32 (2 k-blocks per iter).
// LDS chunk-column XOR swizzle: LDS col c of row r holds global chunk c^((r>>1)&3)
__global__ __launch_bounds__(256, 2) void dual_gemm_kernel(
    const short* __restrict__ xb,  const short* __restrict__ x2b,
    const short* __restrict__ wb,  const short* __restrict__ s2b,
    const float* __restrict__ bmu, const float* __restrict__ bls,
    const float* __restrict__ beps, float* __restrict__ out)
{
    __shared__ __align__(16) short xs[TM * BK];
    __shared__ __align__(16) short x2s[TM * BK];
    __shared__ __align__(16) short ws[TN * BK];
    __shared__ __align__(16) short s2s[TN * BK];

    const int tid = threadIdx.x;
    const int l   = tid & 63;
    const int wv  = tid >> 6;
    const int wr  = wv >> 1;       // wave m (0..1), 64 rows each
    const int wc  = wv & 1;        // wave n (0..1), 64 cols each

    // XCD-aware remap: lid%8 = XCD; each XCD an 8x8 tile region
    const int lid = blockIdx.y * gridDim.x + blockIdx.x;   // 0..511
    const int xcd = lid & 7;
    const int j   = lid >> 3;                              // 0..63
    const int m0  = ((xcd & 3) * 8 + (j >> 3)) * TM;       // 32 m-tiles
    const int n0  = ((xcd >> 2) * 8 + (j & 7)) * TN;       // 16 n-tiles

    floatx16 acc1[2][2] = {};
    floatx16 acc2[2][2] = {};

    // 32x32x16 A/B frag geometry: row = lane&31, k = (lane>>5)*8 + j
    const int rL = l & 31;
    const int h  = l >> 5;
    const int fz = (rL >> 1) & 3;
    // byte offsets within a tile row-block for k-block 0 / 1 (swizzled)
    const int o0 = rL * 64 + ((h)     ^ fz) * 16;   // kb=0: logical chunks 0/1
    const int o1 = rL * 64 + ((2 | h) ^ fz) * 16;   // kb=1: logical chunks 2/3

    // staging: chunk ci = qq*256 + tid; row = ci>>2; swizzled chunk col
    const int row0s = tid >> 2;          // 0..63
    const int row1s = 64 + (tid >> 2);   // 64..127
    const int kcs   = ((tid & 3) ^ ((tid >> 3) & 3)) * 16;
    const int lb0 = (wv * 64) * 16;
    const int lb1 = (256 + wv * 64) * 16;

    const char* xbp  = (const char*)xb;
    const char* x2bp = (const char*)x2b;
    const char* wbp  = (const char*)wb;
    const char* s2bp = (const char*)s2b;

    for (int k0 = 0; k0 < IN_DIM; k0 += BK) {
        size_t gx0 = ((size_t)(m0 + row0s) * IN_DIM + k0) * 2 + kcs;
        size_t gx1 = ((size_t)(m0 + row1s) * IN_DIM + k0) * 2 + kcs;
        size_t gw0 = ((size_t)(n0 + row0s) * IN_DIM + k0) * 2 + kcs;
        size_t gw1 = ((size_t)(n0 + row1s) * IN_DIM + k0) * 2 + kcs;
        cp16(xbp  + gx0, (char*)xs  + lb0);
        cp16(xbp  + gx1, (char*)xs  + lb1);
        cp16(x2bp + gx0, (char*)x2s + lb0);
        cp16(x2bp + gx1, (char*)x2s + lb1);
        cp16(wbp  + gw0, (char*)ws  + lb0);
        cp16(wbp  + gw1, (char*)ws  + lb1);
        cp16(s2bp + gw0, (char*)s2s + lb0);
        cp16(s2bp + gw1, (char*)s2s + lb1);
        __syncthreads();

        {
            short8 a[2][2], b[2][2];   // [mt|nt][kb]
            #pragma unroll
            for (int mt = 0; mt < 2; ++mt) {
                const char* base = (const char*)xs + (wr * 64 + mt * 32) * 64;
                a[mt][0] = *(const short8*)(base + o0);
                a[mt][1] = *(const short8*)(base + o1);
            }
            #pragma unroll
            for (int nt = 0; nt < 2; ++nt) {
                const char* base = (const char*)ws + (wc * 64 + nt * 32) * 64;
                b[nt][0] = *(const short8*)(base + o0);
                b[nt][1] = *(const short8*)(base + o1);
            }
            #pragma unroll
            for (int kb = 0; kb < 2; ++kb)
                #pragma unroll
                for (int mt = 0; mt < 2; ++mt)
                    #pragma unroll
                    for (int nt = 0; nt < 2; ++nt)
                        acc1[mt][nt] = __builtin_amdgcn_mfma_f32_32x32x16_bf16(
                            a[mt][kb], b[nt][kb], acc1[mt][nt], 0, 0, 0);
        }
        {
            short8 a[2][2], b[2][2];
            #pragma unroll
            for (int mt = 0; mt < 2; ++mt) {
                const char* base = (const char*)x2s + (wr * 64 + mt * 32) * 64;
                a[mt][0] = *(const short8*)(base + o0);
                a[mt][1] = *(const short8*)(base + o1);
            }
            #pragma unroll
            for (int nt = 0; nt < 2; ++nt) {
                const char* base = (const char*)s2s + (wc * 64 + nt * 32) * 64;
                b[nt][0] = *(const short8*)(base + o0);
                b[nt][1] = *(const short8*)(base + o1);
            }
            #pragma unroll
            for (int kb = 0; kb < 2; ++kb)
                #pragma unroll
                for (int mt = 0; mt < 2; ++mt)
                    #pragma unroll
                    for (int nt = 0; nt < 2; ++nt)
                        acc2[mt][nt] = __builtin_amdgcn_mfma_f32_32x32x16_bf16(
                            a[mt][kb], b[nt][kb], acc2[mt][nt], 0, 0, 0);
        }
        __syncthreads();
    }

    // epilogue: 32x32 C/D layout: col = lane&31, row = (reg&3)+8*(reg>>2)+4*(lane>>5)
    const int rbase = 4 * h;
    const size_t outOff = (size_t)B_DIM * OUT_DIM;
    #pragma unroll
    for (int nt = 0; nt < 2; ++nt) {
        int col = n0 + wc * 64 + nt * 32 + rL;
        float bsig = __expf(bls[col]);
        float bv   = fmaf(bsig, beps[col], bmu[col]);
        float bs2v = bsig * bsig;
        #pragma unroll
        for (int mt = 0; mt < 2; ++mt) {
            int rowbase = m0 + wr * 64 + mt * 32 + rbase;
            #pragma unroll
            for (int g = 0; g < 4; ++g)
                #pragma unroll
                for (int rr = 0; rr < 4; ++rr) {
                    int reg = g * 4 + rr;
                    size_t idx = (size_t)(rowbase + 8 * g + rr) * OUT_DIM + col;
                    out[idx]          = acc1[mt][nt][reg] + bv;
                    out[outOff + idx] = sqrtf(acc2[mt][nt][reg] + bs2v);
                }
        }
    }
}

// ---- slow fp32 fallback (only if d_ws is too small) ----
__global__ void fallback_kernel(const float* __restrict__ x,
                                const float* __restrict__ wmu,
                                const float* __restrict__ wls,
                                const float* __restrict__ bmu,
                                const float* __restrict__ bls,
                                const float* __restrict__ ew,
                                const float* __restrict__ eb,
                                float* __restrict__ out) {
    int idx = blockIdx.x * blockDim.x + threadIdx.x;
    int b = idx / OUT_DIM, o = idx % OUT_DIM;
    float acc = 0.f, accv = 0.f;
    const float* xr = x   + (size_t)b * IN_DIM;
    const float* mr = wmu + (size_t)o * IN_DIM;
    const float* lr = wls + (size_t)o * IN_DIM;
    const float* er = ew  + (size_t)o * IN_DIM;
    for (int k = 0; k < IN_DIM; ++k) {
        float sg = __expf(lr[k]);
        float wv = fmaf(sg, er[k], mr[k]);
        float xv = xr[k];
        acc  = fmaf(xv, wv, acc);
        accv = fmaf(xv * xv, sg * sg, accv);
    }
    float bsig = __expf(bls[o]);
    out[idx] = acc + fmaf(bsig, eb[o], bmu[o]);
    out[(size_t)B_DIM * OUT_DIM + idx] = sqrtf(accv + bsig * bsig);
}

extern "C" void kernel_launch(void* const* d_in, const int* in_sizes, int n_in,
                              void* d_out, int out_size, void* d_ws, size_t ws_size,
                              hipStream_t stream) {
    const float* x   = (const float*)d_in[0];
    const float* wmu = (const float*)d_in[1];
    const float* wls = (const float*)d_in[2];
    const float* bmu = (const float*)d_in[3];
    const float* bls = (const float*)d_in[4];
    const float* ew  = (const float*)d_in[5];
    const float* eb  = (const float*)d_in[6];
    float* out = (float*)d_out;

    const size_t wn = (size_t)OUT_DIM * IN_DIM;
    const size_t xn = (size_t)B_DIM * IN_DIM;
    const size_t need = (2 * wn + 2 * xn) * sizeof(short);

    if (ws_size < need) {
        int total = B_DIM * OUT_DIM;
        fallback_kernel<<<(total + 255) / 256, 256, 0, stream>>>(
            x, wmu, wls, bmu, bls, ew, eb, out);
        return;
    }

    short* wbf  = (short*)d_ws;
    short* s2bf = wbf + wn;
    short* xbf  = s2bf + wn;
    short* x2bf = xbf + xn;

    prep_kernel<<<6144, 256, 0, stream>>>(wmu, wls, ew, x, wbf, s2bf, xbf, x2bf);

    dim3 grid(OUT_DIM / TN, B_DIM / TM);   // (16, 32) = 512 blocks
    dual_gemm_kernel<<<grid, 256, 0, stream>>>(
        xbf, x2bf, wbf, s2bf, bmu, bls, eb, out);
}